// Round 1
// baseline (571.503 us; speedup 1.0000x reference)
//
#include <hip/hip_runtime.h>

typedef __bf16 bf16x8 __attribute__((ext_vector_type(8)));
typedef float f32x4 __attribute__((ext_vector_type(4)));
typedef unsigned short u16x8 __attribute__((ext_vector_type(8)));
typedef unsigned short u16x4 __attribute__((ext_vector_type(4)));

#define L_LEN 16384
#define TILE 256           // l-positions per block
#define ROWS 270           // TILE + 14 halo rows in LDS
#define XSTR 72            // xT row stride (elements); 144B: conflict-free b128 reads
#define WBT_K 960          // 15 taps * 64 channels
#define NOC 48             // padded compute output channels (3 N-tiles of 16)

__device__ __forceinline__ unsigned short f2bf(float f) {
  unsigned u = __builtin_bit_cast(unsigned, f);
  u += 0x7fffu + ((u >> 16) & 1u);   // RNE
  return (unsigned short)(u >> 16);
}

// compute-oc -> (weight group index, local oc, kernel size). Compute order packs
// small-k channels into N-tile 0 (k=1,3,5,7), tile 1 (k=9,11), tile 2 (k=13,15).
__device__ __forceinline__ void ocmap(int oc, int& gi, int& lo, int& ks) {
  if (oc == 0)       { gi = 0; lo = 0;       ks = 1;  }
  else if (oc <= 5)  { gi = 1; lo = oc - 1;  ks = 3;  }
  else if (oc <= 10) { gi = 2; lo = oc - 6;  ks = 5;  }
  else if (oc <= 15) { gi = 3; lo = oc - 11; ks = 7;  }
  else if (oc <= 20) { gi = 4; lo = oc - 16; ks = 9;  }
  else if (oc <= 25) { gi = 5; lo = oc - 21; ks = 11; }
  else if (oc <= 31) { gi = -1; lo = 0;      ks = 0;  }  // pad
  else if (oc <= 36) { gi = 6; lo = oc - 32; ks = 13; }
  else if (oc <= 41) { gi = 7; lo = oc - 37; ks = 15; }
  else               { gi = -1; lo = 0;      ks = 0;  }  // pad
}

// Repack weights into WbT[oc_c][t*64+c] bf16 (zero outside each kernel's tap
// range) + bias[48] fp32, in d_ws. Re-run every launch (d_ws is re-poisoned).
__global__ void prep_kernel(const float* w1, const float* b1, const float* w3, const float* b3,
                            const float* w5, const float* b5, const float* w7, const float* b7,
                            const float* w9, const float* b9, const float* w11, const float* b11,
                            const float* w13, const float* b13, const float* w15, const float* b15,
                            unsigned short* wbt, float* bias) {
  const float* ws[8] = {w1, w3, w5, w7, w9, w11, w13, w15};
  const float* bs[8] = {b1, b3, b5, b7, b9, b11, b13, b15};
  int gid = blockIdx.x * 256 + threadIdx.x;
  if (gid < NOC * WBT_K) {
    int oc = gid / WBT_K;
    int kk = gid - oc * WBT_K;
    int t = kk >> 6;
    int c = kk & 63;
    int gi, lo, ks;
    ocmap(oc, gi, lo, ks);
    float v = 0.f;
    if (gi >= 0) {
      int pad = (ks - 1) >> 1;
      int dk = t - 7 + pad;                 // tap t maps to weight index dk
      if (dk >= 0 && dk < ks) v = ws[gi][(lo * 64 + c) * ks + dk];
    }
    wbt[gid] = f2bf(v);
  }
  if (gid < NOC) {
    int gi, lo, ks;
    ocmap(gid, gi, lo, ks);
    bias[gid] = (gi >= 0) ? bs[gi][lo] : 0.f;
  }
}

// One K-segment of the main loop. N0/N1 gate N-tiles 0/1 (tile 2 always active).
template <bool N0, bool N1>
__device__ __forceinline__ void kseg(int ks0, int ks1, const unsigned short* xT, int abase,
                                     const unsigned short* w0, const unsigned short* w1p,
                                     const unsigned short* w2p,
                                     f32x4 (&acc0)[4], f32x4 (&acc1)[4], f32x4 (&acc2)[4]) {
  for (int ksx = ks0; ksx < ks1; ++ksx) {
    const int t = ksx >> 1;
    const int coff = (ksx & 1) * 32;
    bf16x8 a[4];
#pragma unroll
    for (int i = 0; i < 4; ++i) {
      u16x8 raw = *(const u16x8*)(&xT[abase + (i * 16 + t) * XSTR + coff]);
      a[i] = __builtin_bit_cast(bf16x8, raw);
    }
    if (N0) {
      bf16x8 bf = __builtin_bit_cast(bf16x8, *(const u16x8*)(w0 + ksx * 32));
#pragma unroll
      for (int i = 0; i < 4; ++i)
        acc0[i] = __builtin_amdgcn_mfma_f32_16x16x32_bf16(a[i], bf, acc0[i], 0, 0, 0);
    }
    if (N1) {
      bf16x8 bf = __builtin_bit_cast(bf16x8, *(const u16x8*)(w1p + ksx * 32));
#pragma unroll
      for (int i = 0; i < 4; ++i)
        acc1[i] = __builtin_amdgcn_mfma_f32_16x16x32_bf16(a[i], bf, acc1[i], 0, 0, 0);
    }
    {
      bf16x8 bf = __builtin_bit_cast(bf16x8, *(const u16x8*)(w2p + ksx * 32));
#pragma unroll
      for (int i = 0; i < 4; ++i)
        acc2[i] = __builtin_amdgcn_mfma_f32_16x16x32_bf16(a[i], bf, acc2[i], 0, 0, 0);
    }
  }
}

__global__ __launch_bounds__(256, 3)
void Inception1d_62680752718395_kernel(const float* __restrict__ x,
                                       const unsigned short* __restrict__ wbt,
                                       const float* __restrict__ bias,
                                       float* __restrict__ out) {
  __shared__ unsigned short xT[ROWS * XSTR];   // bf16 xT[l_local][c], 38.9 KB
  __shared__ unsigned short buf[16 * 272];     // bf16 staging [cc][l], 8.7 KB

  const int tid = threadIdx.x;
  const int bid = blockIdx.x;
  const int tile = bid & 63;
  const int b = bid >> 6;
  const int l0 = tile * TILE;
  const float* xb = x + (size_t)b * 64 * L_LEN;

  // ---- Stage x[b, :, l0-8 .. l0+263] into xT (transposed, bf16) ----
  // 4 chunks of 16 channels: coalesced fp32 -> buf[c][l] (b64 writes), then
  // LDS transpose buf -> xT[l][c] (b128 writes, 8-way ok, tiny volume).
  for (int cb = 0; cb < 4; ++cb) {
    for (int task = tid; task < 16 * 68; task += 256) {
      int cc = task / 68, ch = task - cc * 68;
      const float* xrow = xb + (size_t)(cb * 16 + cc) * L_LEN;
      int l = l0 - 8 + ch * 4;
      float v[4];
      if (l >= 0 && l + 4 <= L_LEN) {
        f32x4 vv = *(const f32x4*)(xrow + l);
#pragma unroll
        for (int e = 0; e < 4; ++e) v[e] = vv[e];
      } else {
#pragma unroll
        for (int e = 0; e < 4; ++e) {
          int le = l + e;
          v[e] = (le >= 0 && le < L_LEN) ? xrow[le] : 0.f;
        }
      }
      u16x4 p;
#pragma unroll
      for (int e = 0; e < 4; ++e) p[e] = f2bf(v[e]);
      *(u16x4*)(&buf[cc * 272 + ch * 4]) = p;
    }
    __syncthreads();
    for (int task = tid; task < 540; task += 256) {
      int oct = task / 270, r = task - oct * 270;
      u16x8 vv;
#pragma unroll
      for (int j = 0; j < 8; ++j) vv[j] = buf[(oct * 8 + j) * 272 + (r + 1)];
      *(u16x8*)(&xT[r * XSTR + cb * 16 + oct * 8]) = vv;
    }
    __syncthreads();
  }

  // ---- MFMA main loop: no barriers from here on ----
  const int lane = tid & 63;
  const int wave = tid >> 6;
  const int n15 = lane & 15;
  const int quad = lane >> 4;

  f32x4 acc0[4], acc1[4], acc2[4];
#pragma unroll
  for (int i = 0; i < 4; ++i) {
    acc0[i] = (f32x4){0.f, 0.f, 0.f, 0.f};
    acc1[i] = (f32x4){0.f, 0.f, 0.f, 0.f};
    acc2[i] = (f32x4){0.f, 0.f, 0.f, 0.f};
  }

  const int abase = (wave * 64 + n15) * XSTR + quad * 8;
  const unsigned short* w0p = wbt + (0 + n15) * WBT_K + quad * 8;
  const unsigned short* w1p = wbt + (16 + n15) * WBT_K + quad * 8;
  const unsigned short* w2p = wbt + (32 + n15) * WBT_K + quad * 8;

  kseg<false, false>(0, 4, xT, abase, w0p, w1p, w2p, acc0, acc1, acc2);   // k13/k15 only
  kseg<false, true >(4, 8, xT, abase, w0p, w1p, w2p, acc0, acc1, acc2);   // + k9/k11
  kseg<true,  true >(8, 22, xT, abase, w0p, w1p, w2p, acc0, acc1, acc2);  // all tiles
  kseg<false, true >(22, 26, xT, abase, w0p, w1p, w2p, acc0, acc1, acc2);
  kseg<false, false>(26, 30, xT, abase, w0p, w1p, w2p, acc0, acc1, acc2);

  // ---- Epilogue: bias + store (compute-oc -> store-oc permutation) ----
  // tile0: oc 0..15 -> 0..15 ; tile1: 16..25 -> 16..25 ; tile2: 32..41 -> 26..35
  const float bs0 = bias[n15];
  const float bs1 = bias[16 + n15];
  const float bs2 = bias[32 + n15];
  const f32x4 bv0 = {bs0, bs0, bs0, bs0};
  const f32x4 bv1 = {bs1, bs1, bs1, bs1};
  const f32x4 bv2 = {bs2, bs2, bs2, bs2};
  const size_t outb = (size_t)b * 36 * L_LEN;
  const int lbase = l0 + wave * 64 + quad * 4;
#pragma unroll
  for (int i = 0; i < 4; ++i) {
    const int lo_ = lbase + i * 16;
    *(f32x4*)(&out[outb + (size_t)n15 * L_LEN + lo_]) = acc0[i] + bv0;
    if (n15 < 10) {
      *(f32x4*)(&out[outb + (size_t)(16 + n15) * L_LEN + lo_]) = acc1[i] + bv1;
      *(f32x4*)(&out[outb + (size_t)(26 + n15) * L_LEN + lo_]) = acc2[i] + bv2;
    }
  }
}

extern "C" void kernel_launch(void* const* d_in, const int* in_sizes, int n_in,
                              void* d_out, int out_size, void* d_ws, size_t ws_size,
                              hipStream_t stream) {
  const float* x = (const float*)d_in[0];
  const float* w[8];
  const float* bb[8];
  for (int i = 0; i < 8; ++i) {
    w[i] = (const float*)d_in[1 + 2 * i];
    bb[i] = (const float*)d_in[2 + 2 * i];
  }
  unsigned short* wbt = (unsigned short*)d_ws;                       // 48*960 bf16 = 92160 B
  float* bias = (float*)((char*)d_ws + NOC * WBT_K * 2);            // +192 B

  prep_kernel<<<(NOC * WBT_K + 255) / 256, 256, 0, stream>>>(
      w[0], bb[0], w[1], bb[1], w[2], bb[2], w[3], bb[3],
      w[4], bb[4], w[5], bb[5], w[6], bb[6], w[7], bb[7], wbt, bias);

  Inception1d_62680752718395_kernel<<<64 * (L_LEN / TILE), 256, 0, stream>>>(
      x, wbt, bias, (float*)d_out);
}

// Round 2
// 553.908 us; speedup vs baseline: 1.0318x; 1.0318x over previous
//
#include <hip/hip_runtime.h>

typedef __bf16 bf16x8 __attribute__((ext_vector_type(8)));
typedef float f32x4 __attribute__((ext_vector_type(4)));
typedef unsigned short u16x8 __attribute__((ext_vector_type(8)));

#define L_LEN 16384
#define TILE 256           // l-positions per block
#define ROWS 270           // TILE + 14 halo rows in LDS
#define XSTR 72            // xT row stride (elements); uniform 8-dword/bank b128 reads
#define WBT_K 960          // 30 ksteps * 32 channels = 15 taps * 64 channels
#define NOC 48             // padded compute output channels (3 N-tiles of 16)

__device__ __forceinline__ unsigned short f2bf(float f) {
  unsigned u = __builtin_bit_cast(unsigned, f);
  u += 0x7fffu + ((u >> 16) & 1u);   // RNE
  return (unsigned short)(u >> 16);
}

// tile0 (oc 0..15: k=1,3,5,7) active ksteps [8,22); tile1 (k=9,11) [4,26); tile2 always
__device__ __forceinline__ bool act0(int s) { return s >= 8 && s < 22; }
__device__ __forceinline__ bool act1(int s) { return s >= 4 && s < 26; }

// compute-oc -> (weight group, local oc, kernel size)
__device__ __forceinline__ void ocmap(int oc, int& gi, int& lo, int& ks) {
  if (oc == 0)       { gi = 0; lo = 0;       ks = 1;  }
  else if (oc <= 5)  { gi = 1; lo = oc - 1;  ks = 3;  }
  else if (oc <= 10) { gi = 2; lo = oc - 6;  ks = 5;  }
  else if (oc <= 15) { gi = 3; lo = oc - 11; ks = 7;  }
  else if (oc <= 20) { gi = 4; lo = oc - 16; ks = 9;  }
  else if (oc <= 25) { gi = 5; lo = oc - 21; ks = 11; }
  else if (oc <= 31) { gi = -1; lo = 0;      ks = 0;  }  // pad
  else if (oc <= 36) { gi = 6; lo = oc - 32; ks = 13; }
  else if (oc <= 41) { gi = 7; lo = oc - 37; ks = 15; }
  else               { gi = -1; lo = 0;      ks = 0;  }  // pad
}

__global__ void prep_kernel(const float* w1, const float* b1, const float* w3, const float* b3,
                            const float* w5, const float* b5, const float* w7, const float* b7,
                            const float* w9, const float* b9, const float* w11, const float* b11,
                            const float* w13, const float* b13, const float* w15, const float* b15,
                            unsigned short* wbt, float* bias) {
  const float* ws[8] = {w1, w3, w5, w7, w9, w11, w13, w15};
  const float* bs[8] = {b1, b3, b5, b7, b9, b11, b13, b15};
  int gid = blockIdx.x * 256 + threadIdx.x;
  if (gid < NOC * WBT_K) {
    int oc = gid / WBT_K;
    int kk = gid - oc * WBT_K;
    int t = kk >> 6;
    int c = kk & 63;
    int gi, lo, ks;
    ocmap(oc, gi, lo, ks);
    float v = 0.f;
    if (gi >= 0) {
      int pad = (ks - 1) >> 1;
      int dk = t - 7 + pad;
      if (dk >= 0 && dk < ks) v = ws[gi][(lo * 64 + c) * ks + dk];
    }
    wbt[gid] = f2bf(v);
  }
  if (gid < NOC) {
    int gi, lo, ks;
    ocmap(gid, gi, lo, ks);
    bias[gid] = (gi >= 0) ? bs[gi][lo] : 0.f;
  }
}

__global__ __launch_bounds__(256, 4)
void Inception1d_62680752718395_kernel(const float* __restrict__ x,
                                       const unsigned short* __restrict__ wbt,
                                       const float* __restrict__ bias,
                                       float* __restrict__ out) {
  __shared__ unsigned short xT[ROWS * XSTR];   // bf16 xT[l_local][c], 38.9 KB (4 blocks/CU)

  const int tid = threadIdx.x;
  const int bid = blockIdx.x;
  const int tile = bid & 63;
  const int b = bid >> 6;
  const int l0 = tile * TILE;
  const float* xb = x + (size_t)b * 64 * L_LEN;

  // ---- Stage x[b, :, l0-7 .. l0+262] into xT transposed (bf16), ONE barrier ----
  // task = j*64 + c: a wave spans all 64 channels at one l-quad -> scalar bf16
  // LDS writes hit 32 banks uniformly (2 lanes share a dword: free). Each thread
  // streams one channel row at 64B stride; the 4 waves' matching iterations
  // consume each 64B line fully (L1-coalesced in time).
#pragma unroll
  for (int it = 0; it < 17; ++it) {
    int task = tid + it * 256;
    int j = task >> 6;
    int c = task & 63;
    const float* xrow = xb + (size_t)c * L_LEN;
    int l = l0 - 8 + j * 4;
    float v[4];
    if (l >= 0 && l + 4 <= L_LEN) {
      f32x4 vv = *(const f32x4*)(xrow + l);
#pragma unroll
      for (int e = 0; e < 4; ++e) v[e] = vv[e];
    } else {
#pragma unroll
      for (int e = 0; e < 4; ++e) {
        int le = l + e;
        v[e] = (le >= 0 && le < L_LEN) ? xrow[le] : 0.f;
      }
    }
#pragma unroll
    for (int e = 0; e < 4; ++e) {
      int r = j * 4 + e - 1;                 // xT[r] = x[l0 - 7 + r]
      if (r >= 0 && r < ROWS) xT[r * XSTR + c] = f2bf(v[e]);
    }
  }
  __syncthreads();

  // ---- Fully-unrolled, prefetch-1 software-pipelined MFMA loop (no barriers) ----
  const int lane = tid & 63;
  const int wave = tid >> 6;
  const int n15 = lane & 15;
  const int quad = lane >> 4;

  f32x4 acc0[4], acc1[4], acc2[4];
#pragma unroll
  for (int i = 0; i < 4; ++i) {
    acc0[i] = (f32x4){0.f, 0.f, 0.f, 0.f};
    acc1[i] = (f32x4){0.f, 0.f, 0.f, 0.f};
    acc2[i] = (f32x4){0.f, 0.f, 0.f, 0.f};
  }

  const int abase = (wave * 64 + n15) * XSTR + quad * 8;
  const unsigned short* w0p = wbt + (0 + n15) * WBT_K + quad * 8;
  const unsigned short* w1p = wbt + (16 + n15) * WBT_K + quad * 8;
  const unsigned short* w2p = wbt + (32 + n15) * WBT_K + quad * 8;

  bf16x8 aC[4];
  bf16x8 w0C = {}, w1C = {}, w2C = {};
  {
    // s = 0 loads (only tile2 active)
    const int t = 0, coff = 0;
#pragma unroll
    for (int i = 0; i < 4; ++i)
      aC[i] = __builtin_bit_cast(bf16x8, *(const u16x8*)(&xT[abase + (i * 16 + t) * XSTR + coff]));
    w2C = __builtin_bit_cast(bf16x8, *(const u16x8*)(w2p + 0));
  }

#pragma unroll
  for (int s = 0; s < 30; ++s) {
    bf16x8 aN[4];
    bf16x8 w0N = {}, w1N = {}, w2N = {};
    if (s + 1 < 30) {
      const int sn = s + 1;
      const int t = sn >> 1;
      const int coff = (sn & 1) * 32;
#pragma unroll
      for (int i = 0; i < 4; ++i)
        aN[i] = __builtin_bit_cast(bf16x8, *(const u16x8*)(&xT[abase + (i * 16 + t) * XSTR + coff]));
      if (act0(sn)) w0N = __builtin_bit_cast(bf16x8, *(const u16x8*)(w0p + sn * 32));
      if (act1(sn)) w1N = __builtin_bit_cast(bf16x8, *(const u16x8*)(w1p + sn * 32));
      w2N = __builtin_bit_cast(bf16x8, *(const u16x8*)(w2p + sn * 32));
    } else {
#pragma unroll
      for (int i = 0; i < 4; ++i) aN[i] = aC[i];
    }
    if (act0(s)) {
#pragma unroll
      for (int i = 0; i < 4; ++i)
        acc0[i] = __builtin_amdgcn_mfma_f32_16x16x32_bf16(aC[i], w0C, acc0[i], 0, 0, 0);
    }
    if (act1(s)) {
#pragma unroll
      for (int i = 0; i < 4; ++i)
        acc1[i] = __builtin_amdgcn_mfma_f32_16x16x32_bf16(aC[i], w1C, acc1[i], 0, 0, 0);
    }
#pragma unroll
    for (int i = 0; i < 4; ++i)
      acc2[i] = __builtin_amdgcn_mfma_f32_16x16x32_bf16(aC[i], w2C, acc2[i], 0, 0, 0);
#pragma unroll
    for (int i = 0; i < 4; ++i) aC[i] = aN[i];
    w0C = w0N; w1C = w1N; w2C = w2N;
  }

  // ---- Epilogue: bias + store (compute-oc -> store-oc permutation) ----
  const float bs0 = bias[n15];
  const float bs1 = bias[16 + n15];
  const float bs2 = bias[32 + n15];
  const f32x4 bv0 = {bs0, bs0, bs0, bs0};
  const f32x4 bv1 = {bs1, bs1, bs1, bs1};
  const f32x4 bv2 = {bs2, bs2, bs2, bs2};
  const size_t outb = (size_t)b * 36 * L_LEN;
  const int lbase = l0 + wave * 64 + quad * 4;
#pragma unroll
  for (int i = 0; i < 4; ++i) {
    const int lo_ = lbase + i * 16;
    *(f32x4*)(&out[outb + (size_t)n15 * L_LEN + lo_]) = acc0[i] + bv0;
    if (n15 < 10) {
      *(f32x4*)(&out[outb + (size_t)(16 + n15) * L_LEN + lo_]) = acc1[i] + bv1;
      *(f32x4*)(&out[outb + (size_t)(26 + n15) * L_LEN + lo_]) = acc2[i] + bv2;
    }
  }
}

extern "C" void kernel_launch(void* const* d_in, const int* in_sizes, int n_in,
                              void* d_out, int out_size, void* d_ws, size_t ws_size,
                              hipStream_t stream) {
  const float* x = (const float*)d_in[0];
  const float* w[8];
  const float* bb[8];
  for (int i = 0; i < 8; ++i) {
    w[i] = (const float*)d_in[1 + 2 * i];
    bb[i] = (const float*)d_in[2 + 2 * i];
  }
  unsigned short* wbt = (unsigned short*)d_ws;                    // 48*960 bf16 = 92160 B
  float* bias = (float*)((char*)d_ws + NOC * WBT_K * 2);          // +192 B

  prep_kernel<<<(NOC * WBT_K + 255) / 256, 256, 0, stream>>>(
      w[0], bb[0], w[1], bb[1], w[2], bb[2], w[3], bb[3],
      w[4], bb[4], w[5], bb[5], w[6], bb[6], w[7], bb[7], wbt, bias);

  Inception1d_62680752718395_kernel<<<64 * (L_LEN / TILE), 256, 0, stream>>>(
      x, wbt, bias, (float*)d_out);
}